// Round 1
// baseline (437.315 us; speedup 1.0000x reference)
//
#include <hip/hip_runtime.h>
#include <math.h>

#define MSZ 4096
#define ISZ 2048
#define NSPLIT 32
#define KC (ISZ / NSPLIT)   // 64 rows per split

// ---------------------------------------------------------------------------
// Kernel 1: split-K partial matvec for the 3 live gates (inpgate, outgate, inp)
// grid = 3 gates x 4 coltiles x NSPLIT splits, block = 256 threads.
// Thread t owns 4 consecutive output columns (one float4 of the weight row) ->
// global_load_dwordx4, fully coalesced. x[k] is wave-uniform -> scalar load.
// ---------------------------------------------------------------------------
__global__ void k_matvec(const float* __restrict__ x,
                         const float* __restrict__ w_inpgate,
                         const float* __restrict__ w_outgate,
                         const float* __restrict__ w_inp,
                         float* __restrict__ z_part)
{
    const int b = blockIdx.x;
    const int gate = b / (4 * NSPLIT);
    const int rem = b % (4 * NSPLIT);
    const int coltile = rem / NSPLIT;
    const int split = rem % NSPLIT;

    const float* W = (gate == 0) ? w_inpgate : (gate == 1) ? w_outgate : w_inp;
    const float4* W4 = (const float4*)W;

    const int c4 = coltile * 256 + threadIdx.x;   // float4 column index, 0..1023
    const int k0 = split * KC;

    float4 acc = {0.f, 0.f, 0.f, 0.f};
    #pragma unroll 8
    for (int ii = 0; ii < KC; ++ii) {
        const float xi = x[k0 + ii];
        const float4 w = W4[(size_t)(k0 + ii) * (MSZ / 4) + c4];
        acc.x += xi * w.x;
        acc.y += xi * w.y;
        acc.z += xi * w.z;
        acc.w += xi * w.w;
    }
    float4* zp4 = (float4*)z_part;
    zp4[((size_t)split * 3 + gate) * (MSZ / 4) + c4] = acc;
}

// ---------------------------------------------------------------------------
// Kernel 2: reduce NSPLIT partials per (gate, col), add bias, apply LSTM math.
// h_t[j] = sigmoid(z_o) * tanh( sigmoid(z_i) * tanh(z_c) )   (c0 == 0)
// 4096 threads total.
// ---------------------------------------------------------------------------
__global__ void k_act(const float* __restrict__ z_part,
                      const float* __restrict__ b_inpgate,
                      const float* __restrict__ b_outgate,
                      const float* __restrict__ b_inp,
                      float* __restrict__ h_t)
{
    const int j = blockIdx.x * 256 + threadIdx.x;  // 0..4095
    float zi = b_inpgate[j];
    float zo = b_outgate[j];
    float zc = b_inp[j];
    #pragma unroll 4
    for (int s = 0; s < NSPLIT; ++s) {
        const float* zp = z_part + (size_t)s * 3 * MSZ;
        zi += zp[0 * MSZ + j];
        zo += zp[1 * MSZ + j];
        zc += zp[2 * MSZ + j];
    }
    const float ig = 1.f / (1.f + __expf(-zi));
    const float og = 1.f / (1.f + __expf(-zo));
    const float ct = tanhf(zc);
    const float c_t = ig * ct;          // forget_gate * c0 == 0
    h_t[j] = og * tanhf(c_t);
}

// ---------------------------------------------------------------------------
// Kernel 3: outer product out[i][j] = w_hid_out[i] * h_t[j]  (4096x4096 fp32).
// One float4 store per thread; row index is uniform per block (4 blocks/row)
// -> w_hid_out[row] becomes a scalar load. Pure write-bound: 64 MiB.
// ---------------------------------------------------------------------------
__global__ void k_outer(const float* __restrict__ w_hid_out,
                        const float* __restrict__ h_t,
                        float4* __restrict__ out4)
{
    const int tid = blockIdx.x * 256 + threadIdx.x;  // 0 .. 4096*1024-1
    const int row = tid >> 10;    // / (4096/4)
    const int j4 = tid & 1023;
    const float w = w_hid_out[row];
    const float4 h = ((const float4*)h_t)[j4];
    float4 o;
    o.x = w * h.x;
    o.y = w * h.y;
    o.z = w * h.z;
    o.w = w * h.w;
    out4[tid] = o;
}

extern "C" void kernel_launch(void* const* d_in, const int* in_sizes, int n_in,
                              void* d_out, int out_size, void* d_ws, size_t ws_size,
                              hipStream_t stream) {
    const float* x          = (const float*)d_in[0];
    // h0 = d_in[1], c0 = d_in[2]: zeros, unused (is_reset==1 and they are zero anyway)
    const float* w_inpgate  = (const float*)d_in[3];
    const float* w_inp      = (const float*)d_in[6];
    const float* w_outgate  = (const float*)d_in[11];
    const float* w_hid_out  = (const float*)d_in[14];
    const float* b_inpgate  = (const float*)d_in[15];
    const float* b_inp      = (const float*)d_in[16];
    const float* b_outgate  = (const float*)d_in[18];

    float* z_part = (float*)d_ws;                       // NSPLIT * 3 * 4096 floats = 1.5 MiB
    float* h_t    = z_part + (size_t)NSPLIT * 3 * MSZ;  // 4096 floats

    k_matvec<<<3 * 4 * NSPLIT, 256, 0, stream>>>(x, w_inpgate, w_outgate, w_inp, z_part);
    k_act<<<MSZ / 256, 256, 0, stream>>>(z_part, b_inpgate, b_outgate, b_inp, h_t);
    k_outer<<<(MSZ * (MSZ / 4)) / 256, 256, 0, stream>>>(w_hid_out, h_t, (float4*)d_out);
}

// Round 3
// 436.715 us; speedup vs baseline: 1.0014x; 1.0014x over previous
//
#include <hip/hip_runtime.h>
#include <math.h>

#define MSZ 4096
#define ISZ 2048
#define NSPLIT 64
#define KC (ISZ / NSPLIT)   // 32 rows per split

typedef float fx4 __attribute__((ext_vector_type(4)));  // native vector: OK for nontemporal builtins

// ---------------------------------------------------------------------------
// Kernel 1: split-K partial matvec for the 3 live gates (inpgate, outgate, inp)
// grid = 3 gates x 4 coltiles x NSPLIT splits = 768 blocks = 3 blocks/CU exact.
// Thread t owns 4 consecutive output columns (one float4 of the weight row) ->
// global_load_dwordx4, fully coalesced. x[k] is wave-uniform -> s_load.
// ---------------------------------------------------------------------------
__global__ void k_matvec(const float* __restrict__ x,
                         const float* __restrict__ w_inpgate,
                         const float* __restrict__ w_outgate,
                         const float* __restrict__ w_inp,
                         float* __restrict__ z_part)
{
    const int b = blockIdx.x;
    const int gate = b / (4 * NSPLIT);
    const int rem = b % (4 * NSPLIT);
    const int coltile = rem / NSPLIT;
    const int split = rem % NSPLIT;

    const float* W = (gate == 0) ? w_inpgate : (gate == 1) ? w_outgate : w_inp;
    const fx4* W4 = (const fx4*)W;

    const int c4 = coltile * 256 + threadIdx.x;   // float4 column index, 0..1023
    const int k0 = split * KC;

    fx4 acc = {0.f, 0.f, 0.f, 0.f};
    #pragma unroll 8
    for (int ii = 0; ii < KC; ++ii) {
        const float xi = x[k0 + ii];
        const fx4 w = W4[(size_t)(k0 + ii) * (MSZ / 4) + c4];
        acc += xi * w;
    }
    fx4* zp4 = (fx4*)z_part;
    zp4[((size_t)split * 3 + gate) * (MSZ / 4) + c4] = acc;
}

// ---------------------------------------------------------------------------
// Kernel 2: reduce NSPLIT partials per (gate, col), add bias, apply LSTM math.
// h_t[j] = sigmoid(z_o) * tanh( sigmoid(z_i) * tanh(z_c) )   (c0 == 0)
// 4096 threads; reads 3 MB of partials (L2-resident).
// ---------------------------------------------------------------------------
__global__ void k_act(const float* __restrict__ z_part,
                      const float* __restrict__ b_inpgate,
                      const float* __restrict__ b_outgate,
                      const float* __restrict__ b_inp,
                      float* __restrict__ h_t)
{
    const int j = blockIdx.x * 256 + threadIdx.x;  // 0..4095
    float zi = b_inpgate[j];
    float zo = b_outgate[j];
    float zc = b_inp[j];
    #pragma unroll 8
    for (int s = 0; s < NSPLIT; ++s) {
        const float* zp = z_part + (size_t)s * 3 * MSZ;
        zi += zp[0 * MSZ + j];
        zo += zp[1 * MSZ + j];
        zc += zp[2 * MSZ + j];
    }
    const float ig = 1.f / (1.f + __expf(-zi));
    const float og = 1.f / (1.f + __expf(-zo));
    const float ct = tanhf(zc);
    const float c_t = ig * ct;          // forget_gate * c0 == 0
    h_t[j] = og * tanhf(c_t);
}

// ---------------------------------------------------------------------------
// Kernel 3: outer product out[i][j] = w_hid_out[i] * h_t[j]  (4096x4096 fp32).
// One float4 non-temporal store per thread; row uniform per wave ->
// w_hid_out[row] is an L1-hit scalar-ish load. Pure write-bound: 64 MiB.
// ---------------------------------------------------------------------------
__global__ void k_outer(const float* __restrict__ w_hid_out,
                        const float* __restrict__ h_t,
                        fx4* __restrict__ out4)
{
    const int tid = blockIdx.x * 256 + threadIdx.x;  // 0 .. 4096*1024-1
    const int row = tid >> 10;    // / (4096/4)
    const int j4 = tid & 1023;
    const float w = w_hid_out[row];
    const fx4 h = ((const fx4*)h_t)[j4];
    const fx4 o = w * h;
    __builtin_nontemporal_store(o, &out4[tid]);
}

extern "C" void kernel_launch(void* const* d_in, const int* in_sizes, int n_in,
                              void* d_out, int out_size, void* d_ws, size_t ws_size,
                              hipStream_t stream) {
    const float* x          = (const float*)d_in[0];
    // h0 = d_in[1], c0 = d_in[2]: zeros, unused (is_reset==1 and they are zeros anyway)
    const float* w_inpgate  = (const float*)d_in[3];
    const float* w_inp      = (const float*)d_in[6];
    const float* w_outgate  = (const float*)d_in[11];
    const float* w_hid_out  = (const float*)d_in[14];
    const float* b_inpgate  = (const float*)d_in[15];
    const float* b_inp      = (const float*)d_in[16];
    const float* b_outgate  = (const float*)d_in[18];

    float* z_part = (float*)d_ws;                       // NSPLIT * 3 * 4096 floats = 3 MiB
    float* h_t    = z_part + (size_t)NSPLIT * 3 * MSZ;  // 4096 floats

    k_matvec<<<3 * 4 * NSPLIT, 256, 0, stream>>>(x, w_inpgate, w_outgate, w_inp, z_part);
    k_act<<<MSZ / 256, 256, 0, stream>>>(z_part, b_inpgate, b_outgate, b_inp, h_t);
    k_outer<<<(MSZ * (MSZ / 4)) / 256, 256, 0, stream>>>(w_hid_out, h_t, (fx4*)d_out);
}